// Round 8
// baseline (620.930 us; speedup 1.0000x reference)
//
#include <hip/hip_runtime.h>
#include <hip/hip_bf16.h>
#include <math.h>

typedef __hip_bfloat16 bf16;
typedef float f4 __attribute__((ext_vector_type(4)));
typedef short s8 __attribute__((ext_vector_type(8)));      // 8 bf16 fragment (4 VGPR)
typedef unsigned int u2 __attribute__((ext_vector_type(2)));
typedef unsigned int u4v __attribute__((ext_vector_type(4)));

// async global->LDS, 16B per lane; LDS dest = wave-uniform base + lane*16
__device__ __forceinline__ void gload16(const void* g, char* l) {
  __builtin_amdgcn_global_load_lds(
      (const __attribute__((address_space(1))) unsigned int*)g,
      (__attribute__((address_space(3))) unsigned int*)l, 16, 0, 0);
}
__device__ __forceinline__ unsigned short bfr(float f) {
  bf16 h = __float2bfloat16(f);
  return *(unsigned short*)&h;
}
__device__ __forceinline__ unsigned int pk2(float a, float b) {
  return (unsigned int)bfr(a) | ((unsigned int)bfr(b) << 16);
}
// truncating bf16x2 pack (lo=a, hi=b): 1 v_perm_b32
__device__ __forceinline__ unsigned int pkt(float a, float b) {
  return __builtin_amdgcn_perm(__float_as_uint(b), __float_as_uint(a), 0x07060302u);
}

// ---------------- weight prep: fp32 -> bf16 (+ zero page). w_in/w_c3 handled
// by prep_fold (w_in is folded into the 3x3 conv weights).
__global__ __launch_bounds__(256) void prep_w(
    const float* __restrict__ wq, const float* __restrict__ wkv,
    const float* __restrict__ wo, const float* __restrict__ win,
    const float* __restrict__ wc3, const float* __restrict__ wc1,
    const float* __restrict__ wout, ushort* __restrict__ cw)
{
  int i = blockIdx.x * 256 + threadIdx.x;
  float v;
  if (i < 131072) v = wq[i];
  else if (i < 393216) v = wkv[i - 131072];
  else if (i < 524288) v = wo[i - 393216];
  else if (i < 1146880) return;                  // w_in + w_c3 regions: prep_fold
  else if (i < 1212416) v = wc1[i - 1146880];
  else if (i < 1228800) v = wout[i - 1212416];
  else if (i < 1230848) { cw[i] = 0; return; }   // zero page
  else return;
  cw[i] = bfr(v);
}

// ---------------- fold w_in into w_c3:  wf[m][tap][i] = sum_c wc3[m][c][tap]*win[c][i]
// Also emits border-bias tables T[lyr][9][256]:
//   k=0: sum all taps of sb; 1: top row (ky=0); 2: bottom; 3: left col (kx=0);
//   4: right; 5..8: corner taps tl,tr,bl,br   where sb[m][tap]=sum_c wc3*b_in.
// One block per (lyr, m); 128 threads (thread = i for compute, = c for staging).
__global__ __launch_bounds__(128) void prep_fold(
    const float* __restrict__ wc3, const float* __restrict__ win,
    const float* __restrict__ b_in, ushort* __restrict__ cw3out,
    float* __restrict__ T)
{
  __shared__ float col[128][9];
  __shared__ float sred[2][9];
  const int lyr = blockIdx.x >> 8, m = blockIdx.x & 255;
  const int tid = threadIdx.x;
  const float* src = wc3 + (((size_t)lyr * 256 + m) * 128 + tid) * 9;
#pragma unroll
  for (int t = 0; t < 9; ++t) col[tid][t] = src[t];
  // sb[tap] = sum_c col[c][tap]*b_in[c]  (reduce own product across 128 threads)
  float bi = b_in[lyr * 128 + tid];
  float sb[9];
#pragma unroll
  for (int t = 0; t < 9; ++t) {
    float v = col[tid][t] * bi;
    v += __shfl_xor(v, 1, 64);  v += __shfl_xor(v, 2, 64);
    v += __shfl_xor(v, 4, 64);  v += __shfl_xor(v, 8, 64);
    v += __shfl_xor(v, 16, 64); v += __shfl_xor(v, 32, 64);
    sb[t] = v;
  }
  if ((tid & 63) == 0) {
#pragma unroll
    for (int t = 0; t < 9; ++t) sred[tid >> 6][t] = sb[t];
  }
  __syncthreads();
  // folded weights: thread i computes the 9 taps' dot over c
  float acc[9] = {0.f,0.f,0.f,0.f,0.f,0.f,0.f,0.f,0.f};
  const float* wrow = win + (size_t)lyr * 16384 + tid;
  for (int c = 0; c < 128; ++c) {
    float wv = wrow[(size_t)c * 128];
#pragma unroll
    for (int t = 0; t < 9; ++t) acc[t] += col[c][t] * wv;
  }
  ushort* dst = cw3out + (size_t)lyr * 294912 + (size_t)m * 1152 + tid;
#pragma unroll
  for (int t = 0; t < 9; ++t) dst[t * 128] = bfr(acc[t]);
  if (tid == 0) {
    float s[9];
#pragma unroll
    for (int t = 0; t < 9; ++t) s[t] = sred[0][t] + sred[1][t];
    float* Tl = T + lyr * 2304;
    Tl[0 * 256 + m] = s[0]+s[1]+s[2]+s[3]+s[4]+s[5]+s[6]+s[7]+s[8];
    Tl[1 * 256 + m] = s[0] + s[1] + s[2];
    Tl[2 * 256 + m] = s[6] + s[7] + s[8];
    Tl[3 * 256 + m] = s[0] + s[3] + s[6];
    Tl[4 * 256 + m] = s[2] + s[5] + s[8];
    Tl[5 * 256 + m] = s[0];
    Tl[6 * 256 + m] = s[2];
    Tl[7 * 256 + m] = s[6];
    Tl[8 * 256 + m] = s[8];
  }
}

// ---------------- LayerNorm over channels -> NHWC bf16 (NCHW f32 input; only
// the first LN remains standalone — the rest are fused into GEMM epilogues)
template<bool NCHW>
__global__ __launch_bounds__(256) void ln_nhwc(
    const float* __restrict__ x, const float* __restrict__ g,
    const float* __restrict__ b, ushort* __restrict__ y)
{
  const int p = blockIdx.x * 256 + threadIdx.x;
  f4 v[32];
  float s = 0.f, s2 = 0.f;
  if constexpr (NCHW) {
#pragma unroll
    for (int i = 0; i < 32; ++i)
#pragma unroll
      for (int j = 0; j < 4; ++j) {
        float t = x[(size_t)(i * 4 + j) * 65536 + p];
        v[i][j] = t; s += t; s2 += t * t;
      }
  } else {
    const f4* base = (const f4*)(x + (size_t)p * 128);
#pragma unroll
    for (int i = 0; i < 32; ++i) {
      v[i] = base[i];
#pragma unroll
      for (int j = 0; j < 4; ++j) { s += v[i][j]; s2 += v[i][j] * v[i][j]; }
    }
  }
  float mean = s * (1.f / 128.f);
  float var = s2 * (1.f / 128.f) - mean * mean;
  var = var > 0.f ? var : 0.f;
  float inv = 1.f / (sqrtf(var) + 1e-5f);
  u2* dst = (u2*)(y + (size_t)p * 128);
#pragma unroll
  for (int i = 0; i < 32; ++i) {
    f4 gg = *(const f4*)(g + i * 4);
    f4 bb = *(const f4*)(b + i * 4);
    float f0 = (v[i][0] - mean) * inv * gg[0] + bb[0];
    float f1 = (v[i][1] - mean) * inv * gg[1] + bb[1];
    float f2 = (v[i][2] - mean) * inv * gg[2] + bb[2];
    float f3 = (v[i][3] - mean) * inv * gg[3] + bb[3];
    u2 st; st.x = pk2(f0, f1); st.y = pk2(f2, f3);
    dst[i] = st;
  }
}

// ---------------- MFMA GEMM: C_nhwc[n][m] = sum_k A[m][k] * X[n][k]
// MODE 0: bf16 out + bias
// MODE 1: f32 out + bias + res(NHWC f32)
// MODE 2: NCHW f32 out + bias + res(NHWC f32)
// MODE 3: MODE 1 + bf16 mirror to out2
// MODE 4: f32 out + bias + res(NCHW f32)
// MODE 5: MODE 1 + fused LayerNorm over the 128 out-channels -> xn (bf16 NHWC)
// MODE 6: MODE 4 + fused LayerNorm -> xn
// LN fusion requires M==128, gridDim.y==1 (block holds full channel vector).
template<int MODE>
__global__ __launch_bounds__(256) void gemm_nhwc(
    const ushort* __restrict__ A, const ushort* __restrict__ X,
    const float* __restrict__ bias, const float* __restrict__ res,
    void* __restrict__ out, ushort* __restrict__ out2,
    const float* __restrict__ lng, const float* __restrict__ lnb,
    ushort* __restrict__ xn, const int K, const int M)
{
  __shared__ __align__(16) char sm[32768];   // A-tile [128][64] @0, X-tile @16384 (xor-swizzled)
  const int tid = threadIdx.x, w = tid >> 6, l = tid & 63;
  const int quad = l >> 4, l15 = l & 15;
  const int n0 = blockIdx.x * 128, m0 = blockIdx.y * 128;
  const int mh = (w & 1) * 64, nh = (w >> 1) * 64;
  const f4 fz = {0.f, 0.f, 0.f, 0.f};
  f4 acc[4][4];
#pragma unroll
  for (int a = 0; a < 4; ++a)
#pragma unroll
    for (int b2 = 0; b2 < 4; ++b2) acc[a][b2] = fz;

  const int KI = K >> 6;
  for (int kk = 0; kk < KI; ++kk) {
    if (kk) __syncthreads();
    const int k0 = kk << 6;
#pragma unroll
    for (int j = 0; j < 4; ++j) {
      int p = j * 256 + tid, r = p >> 3, c = (p & 7) ^ (r & 7);
      gload16(A + (size_t)(m0 + r) * K + k0 + c * 8, sm + (j * 256 + w * 64) * 16);
    }
#pragma unroll
    for (int j = 0; j < 4; ++j) {
      int p = j * 256 + tid, r = p >> 3, c = (p & 7) ^ (r & 7);
      gload16(X + (size_t)(n0 + r) * K + k0 + c * 8, sm + 16384 + (j * 256 + w * 64) * 16);
    }
    __syncthreads();
#pragma unroll
    for (int ks = 0; ks < 2; ++ks) {
      s8 af[4], bx[4];
#pragma unroll
      for (int mt = 0; mt < 4; ++mt) {
        int rr = mh + mt * 16 + l15;
        af[mt] = *(const s8*)(sm + rr * 128 + (((ks * 4 + quad) ^ (rr & 7)) << 4));
      }
#pragma unroll
      for (int nt = 0; nt < 4; ++nt) {
        int rr = nh + nt * 16 + l15;
        bx[nt] = *(const s8*)(sm + 16384 + rr * 128 + (((ks * 4 + quad) ^ (rr & 7)) << 4));
      }
#pragma unroll
      for (int mt = 0; mt < 4; ++mt)
#pragma unroll
        for (int nt = 0; nt < 4; ++nt)
          acc[mt][nt] = __builtin_amdgcn_mfma_f32_16x16x32_bf16(af[mt], bx[nt], acc[mt][nt], 0, 0, 0);
    }
  }

  if constexpr (MODE == 5 || MODE == 6) {
    // ---- fused bias + residual + write XH f32 + per-pixel LayerNorm -> xn
    float s1[4] = {0.f, 0.f, 0.f, 0.f}, s2[4] = {0.f, 0.f, 0.f, 0.f};
#pragma unroll
    for (int mt = 0; mt < 4; ++mt) {
      const int m = mh + mt * 16 + quad * 4;
      f4 bb = *(const f4*)(bias + m);
#pragma unroll
      for (int nt = 0; nt < 4; ++nt) {
        const int n = n0 + nh + nt * 16 + l15;
        f4 v = acc[mt][nt] + bb;
        if constexpr (MODE == 5) {
          f4 r = *(const f4*)(res + (size_t)n * 128 + m);
          v += r;
        } else {
          f4 r;
#pragma unroll
          for (int i = 0; i < 4; ++i) r[i] = res[(size_t)(m + i) * 65536 + n];
          v += r;
        }
        *(f4*)((float*)out + (size_t)n * 128 + m) = v;
        acc[mt][nt] = v;
        s1[nt] += v[0] + v[1] + v[2] + v[3];
        s2[nt] += v[0] * v[0] + v[1] * v[1] + v[2] * v[2] + v[3] * v[3];
      }
    }
    __syncthreads();               // all K-loop LDS reads done; reuse sm
    float* pb = (float*)sm;        // [2 halves][128 pixels][2] floats = 2KB
#pragma unroll
    for (int nt = 0; nt < 4; ++nt) {
      float a1 = s1[nt], a2 = s2[nt];
      a1 += __shfl_xor(a1, 16, 64); a1 += __shfl_xor(a1, 32, 64);
      a2 += __shfl_xor(a2, 16, 64); a2 += __shfl_xor(a2, 32, 64);
      s1[nt] = a1; s2[nt] = a2;
      if (quad == 0) {
        int pn = nh + nt * 16 + l15;
        pb[((w & 1) * 128 + pn) * 2]     = a1;
        pb[((w & 1) * 128 + pn) * 2 + 1] = a2;
      }
    }
    __syncthreads();
#pragma unroll
    for (int nt = 0; nt < 4; ++nt) {
      int pn = nh + nt * 16 + l15;
      float t1 = s1[nt] + pb[((1 - (w & 1)) * 128 + pn) * 2];
      float t2 = s2[nt] + pb[((1 - (w & 1)) * 128 + pn) * 2 + 1];
      float mean = t1 * (1.f / 128.f);
      float var = t2 * (1.f / 128.f) - mean * mean;
      var = var > 0.f ? var : 0.f;
      s1[nt] = mean;
      s2[nt] = 1.f / (sqrtf(var) + 1e-5f);
    }
#pragma unroll
    for (int mt = 0; mt < 4; ++mt) {
      const int m = mh + mt * 16 + quad * 4;
      f4 gg = *(const f4*)(lng + m);
      f4 b2 = *(const f4*)(lnb + m);
#pragma unroll
      for (int nt = 0; nt < 4; ++nt) {
        const int n = n0 + nh + nt * 16 + l15;
        f4 v = acc[mt][nt];
        float mean = s1[nt], inv = s2[nt];
        float f0 = (v[0] - mean) * inv * gg[0] + b2[0];
        float f1 = (v[1] - mean) * inv * gg[1] + b2[1];
        float f2 = (v[2] - mean) * inv * gg[2] + b2[2];
        float f3 = (v[3] - mean) * inv * gg[3] + b2[3];
        u2 st; st.x = pk2(f0, f1); st.y = pk2(f2, f3);
        *(u2*)(xn + (size_t)n * 128 + m) = st;
      }
    }
    return;
  }

#pragma unroll
  for (int mt = 0; mt < 4; ++mt) {
#pragma unroll
    for (int nt = 0; nt < 4; ++nt) {
      const int m = m0 + mh + mt * 16 + quad * 4;
      const int n = n0 + nh + nt * 16 + l15;
      f4 bb = *(const f4*)(bias + m);
      f4 v = acc[mt][nt] + bb;
      if constexpr (MODE == 0) {
        u2 st; st.x = pk2(v[0], v[1]); st.y = pk2(v[2], v[3]);
        *(u2*)((ushort*)out + (size_t)n * M + m) = st;
      } else if constexpr (MODE == 1 || MODE == 3) {
        f4 r = *(const f4*)(res + (size_t)n * M + m);
        v += r;
        *(f4*)((float*)out + (size_t)n * M + m) = v;
        if constexpr (MODE == 3) {
          u2 st; st.x = pk2(v[0], v[1]); st.y = pk2(v[2], v[3]);
          *(u2*)(out2 + (size_t)n * M + m) = st;
        }
      } else if constexpr (MODE == 4) {
        f4 r;
#pragma unroll
        for (int i = 0; i < 4; ++i) r[i] = res[(size_t)(m + i) * 65536 + n];
        v += r;
        *(f4*)((float*)out + (size_t)n * M + m) = v;
      } else {
        f4 r = *(const f4*)(res + (size_t)n * M + m);
#pragma unroll
        for (int i = 0; i < 4; ++i)
          ((float*)out)[(size_t)(m + i) * 65536 + n] = v[i] + r[i];
      }
    }
  }
}

// ---------------- 3x3 conv (w_in FOLDED IN) as implicit MFMA GEMM (K=9*128)
// + border-aware folded b_in + b_c3 + exact GELU -> bf16.
// Reads XN directly; tap validity bias from T tables (see prep_fold).
__global__ __launch_bounds__(256) void conv3_kernel(
    const ushort* __restrict__ A, const ushort* __restrict__ X,
    const float* __restrict__ bias, ushort* __restrict__ out,
    const ushort* __restrict__ zp, const float* __restrict__ T)
{
  __shared__ __align__(16) char sm[32768];
  const int tid = threadIdx.x, w = tid >> 6, l = tid & 63;
  const int quad = l >> 4, l15 = l & 15;
  const int n0 = blockIdx.x * 128, m0 = blockIdx.y * 128;
  const int mh = (w & 1) * 64, nh = (w >> 1) * 64;
  const f4 fz = {0.f, 0.f, 0.f, 0.f};
  f4 acc[4][4];
#pragma unroll
  for (int a = 0; a < 4; ++a)
#pragma unroll
    for (int b2 = 0; b2 < 4; ++b2) acc[a][b2] = fz;

  for (int kk = 0; kk < 18; ++kk) {
    if (kk) __syncthreads();
    const int tap = kk >> 1, ky = tap / 3, kx = tap - ky * 3;
    const int dn = (ky - 1) * 256 + (kx - 1);
    const int kseg = (kk & 1) << 6;
#pragma unroll
    for (int j = 0; j < 4; ++j) {
      int p = j * 256 + tid, r = p >> 3, c = (p & 7) ^ (r & 7);
      gload16(A + (size_t)(m0 + r) * 1152 + kk * 64 + c * 8, sm + (j * 256 + w * 64) * 16);
    }
#pragma unroll
    for (int j = 0; j < 4; ++j) {
      int p = j * 256 + tid, r = p >> 3, c = (p & 7) ^ (r & 7);
      int nl = n0 + r;
      int ys = (nl >> 8) + ky - 1, xs = (nl & 255) + kx - 1;
      const ushort* gp = ((unsigned)ys < 256u && (unsigned)xs < 256u)
                         ? X + (size_t)(nl + dn) * 128 + kseg + c * 8 : zp;
      gload16(gp, sm + 16384 + (j * 256 + w * 64) * 16);
    }
    __syncthreads();
#pragma unroll
    for (int ks = 0; ks < 2; ++ks) {
      s8 af[4], bx[4];
#pragma unroll
      for (int mt = 0; mt < 4; ++mt) {
        int rr = mh + mt * 16 + l15;
        af[mt] = *(const s8*)(sm + rr * 128 + (((ks * 4 + quad) ^ (rr & 7)) << 4));
      }
#pragma unroll
      for (int nt = 0; nt < 4; ++nt) {
        int rr = nh + nt * 16 + l15;
        bx[nt] = *(const s8*)(sm + 16384 + rr * 128 + (((ks * 4 + quad) ^ (rr & 7)) << 4));
      }
#pragma unroll
      for (int mt = 0; mt < 4; ++mt)
#pragma unroll
        for (int nt = 0; nt < 4; ++nt)
          acc[mt][nt] = __builtin_amdgcn_mfma_f32_16x16x32_bf16(af[mt], bx[nt], acc[mt][nt], 0, 0, 0);
    }
  }
  // epilogue: folded-bias with border correction, then GELU
  const int y = n0 >> 8;                 // block-uniform (block spans half a row)
  const bool y0 = (y == 0), y1 = (y == 255);
  const int xbase = (n0 & 255) + nh;
#pragma unroll
  for (int mt = 0; mt < 4; ++mt) {
    const int m = m0 + mh + mt * 16 + quad * 4;
    f4 base = *(const f4*)(bias + m) + *(const f4*)(T + m);
    f4 Lc = *(const f4*)(T + 3 * 256 + m);
    f4 Rc = *(const f4*)(T + 4 * 256 + m);
    if (y0) {
      base -= *(const f4*)(T + 1 * 256 + m);
      Lc -= *(const f4*)(T + 5 * 256 + m);
      Rc -= *(const f4*)(T + 6 * 256 + m);
    }
    if (y1) {
      base -= *(const f4*)(T + 2 * 256 + m);
      Lc -= *(const f4*)(T + 7 * 256 + m);
      Rc -= *(const f4*)(T + 8 * 256 + m);
    }
#pragma unroll
    for (int nt = 0; nt < 4; ++nt) {
      const int n = n0 + nh + nt * 16 + l15;
      const int x = xbase + nt * 16 + l15;
      float fx0 = (x == 0) ? 1.f : 0.f;
      float fx1 = (x == 255) ? 1.f : 0.f;
      f4 v = acc[mt][nt] + base - Lc * fx0 - Rc * fx1;
      float g0 = 0.5f * v[0] * (1.f + erff(v[0] * 0.70710678118f));
      float g1 = 0.5f * v[1] * (1.f + erff(v[1] * 0.70710678118f));
      float g2 = 0.5f * v[2] * (1.f + erff(v[2] * 0.70710678118f));
      float g3 = 0.5f * v[3] * (1.f + erff(v[3] * 0.70710678118f));
      u2 st; st.x = pk2(g0, g1); st.y = pk2(g2, g3);
      *(u2*)(out + (size_t)n * 256 + m) = st;
    }
  }
}

// ---------------- fully-fused window attention, 512 threads (8 waves) --------
// One block per (window, head). Wave w owns i-tokens [w*32, w*32+32).
// r5-proven kernel (118.5us): LDS 144KB, LDS-staged X/W, P in LDS, setprio on
// flash MFMA clusters. (in-register P via shuffle REGRESSED: ds_bpermute uses
// the LDS pipe, conflicts 4.98M->7.08M.)
__global__ __launch_bounds__(512) void attn_kernel(
    const ushort* __restrict__ xn, const ushort* __restrict__ wq,
    const ushort* __restrict__ wkv, ushort* __restrict__ ao)
{
  __shared__ __align__(16) char sm[147456];
  const int tid = threadIdx.x, w = tid >> 6, l = tid & 63;
  const int quad = l >> 4, l15 = l & 15;
  const int win = blockIdx.x, head = blockIdx.y;
  const int nbase = ((win >> 4) << 12) + ((win & 15) << 4);
  char* RX  = sm;                  // 65536
  char* RW  = sm + 65536;          // 49152: Wq@0, Wk@16384, Wv@32768; later O
  char* RK  = sm + 114688;         // 32768 [tok][64d]
  char* RVT = sm;                  // 32768 [64d][256tok]
  char* Pw  = sm + 32768 + w * 4096;  // wave-private P [32 i][64 j]
  char* RO  = RW;                  // O [256 tok][64 d]
  const f4 fz = {0.f, 0.f, 0.f, 0.f};

  // ---- stage Xwin [256 tok][128 ch] + Wq + Wk + Wv (single shot)
#pragma unroll
  for (int j = 0; j < 8; ++j) {
    int p = j * 512 + tid, r = p >> 4, c = (p & 15) ^ (r & 15);
    int n = nbase + ((r >> 4) << 8) + (r & 15);
    gload16(xn + (size_t)n * 128 + c * 8, RX + (j * 512 + w * 64) * 16);
  }
  {
    const ushort* wpq = wq + (size_t)head * 64 * 128;
    const ushort* wpk = wkv + (size_t)head * 64 * 128;
    const ushort* wpv = wkv + (size_t)(512 + head * 64) * 128;
#pragma unroll
    for (int j = 0; j < 2; ++j) {
      int p = j * 512 + tid, r = p >> 4, c = (p & 15) ^ (r & 15);
      gload16(wpq + (size_t)r * 128 + c * 8, RW + (j * 512 + w * 64) * 16);
    }
#pragma unroll
    for (int j = 0; j < 2; ++j) {
      int p = j * 512 + tid, r = p >> 4, c = (p & 15) ^ (r & 15);
      gload16(wpk + (size_t)r * 128 + c * 8, RW + 16384 + (j * 512 + w * 64) * 16);
    }
#pragma unroll
    for (int j = 0; j < 2; ++j) {
      int p = j * 512 + tid, r = p >> 4, c = (p & 15) ^ (r & 15);
      gload16(wpv + (size_t)r * 128 + c * 8, RW + 32768 + (j * 512 + w * 64) * 16);
    }
  }
  __syncthreads();   // A: Xwin + all W ready

  // ---- Q projection -> registers (B-fragment layout via shuffles)
  s8 bq[2][2];
  {
    f4 acc[4][2];
#pragma unroll
    for (int a = 0; a < 4; ++a) { acc[a][0] = fz; acc[a][1] = fz; }
#pragma unroll
    for (int ks = 0; ks < 4; ++ks) {
      s8 af[4], bx[2];
#pragma unroll
      for (int mt = 0; mt < 4; ++mt) {
        int rr = mt * 16 + l15;
        af[mt] = *(const s8*)(RW + rr * 256 + (((ks * 4 + quad) ^ (rr & 15)) << 4));
      }
#pragma unroll
      for (int nt = 0; nt < 2; ++nt) {
        int rr = w * 32 + nt * 16 + l15;
        bx[nt] = *(const s8*)(RX + rr * 256 + (((ks * 4 + quad) ^ (rr & 15)) << 4));
      }
#pragma unroll
      for (int mt = 0; mt < 4; ++mt)
#pragma unroll
        for (int nt = 0; nt < 2; ++nt)
          acc[mt][nt] = __builtin_amdgcn_mfma_f32_16x16x32_bf16(af[mt], bx[nt], acc[mt][nt], 0, 0, 0);
    }
    // C layout: lane(quad,l15) holds Q[d=mt*16+quad*4+reg][tok=w*32+nt*16+l15].
    // B-frag needs: lane(quad,l15) holds d=ks*32+quad*8+j at same tok.
#pragma unroll
    for (int nt = 0; nt < 2; ++nt) {
      unsigned pd[4][2];
#pragma unroll
      for (int mt = 0; mt < 4; ++mt) {
        pd[mt][0] = pkt(acc[mt][nt][0], acc[mt][nt][1]);
        pd[mt][1] = pkt(acc[mt][nt][2], acc[mt][nt][3]);
      }
#pragma unroll
      for (int ks = 0; ks < 2; ++ks) {
        u4v t;
#pragma unroll
        for (int dj = 0; dj < 4; ++dj) {
          int srcl = l15 + (((quad & 1) * 2 + (dj >> 1)) << 4);
          unsigned va = (unsigned)__shfl((int)pd[2 * ks][dj & 1], srcl, 64);
          unsigned vb = (unsigned)__shfl((int)pd[2 * ks + 1][dj & 1], srcl, 64);
          t[dj] = (quad < 2) ? va : vb;
        }
        bq[nt][ks] = __builtin_bit_cast(s8, t);
      }
    }
  }

  // ---- K projection -> RK [tok][64d] swizzled
  {
    f4 acc[4][2];
#pragma unroll
    for (int a = 0; a < 4; ++a) { acc[a][0] = fz; acc[a][1] = fz; }
#pragma unroll
    for (int ks = 0; ks < 4; ++ks) {
      s8 af[4], bx[2];
#pragma unroll
      for (int mt = 0; mt < 4; ++mt) {
        int rr = mt * 16 + l15;
        af[mt] = *(const s8*)(RW + 16384 + rr * 256 + (((ks * 4 + quad) ^ (rr & 15)) << 4));
      }
#pragma unroll
      for (int nt = 0; nt < 2; ++nt) {
        int rr = w * 32 + nt * 16 + l15;
        bx[nt] = *(const s8*)(RX + rr * 256 + (((ks * 4 + quad) ^ (rr & 15)) << 4));
      }
#pragma unroll
      for (int mt = 0; mt < 4; ++mt)
#pragma unroll
        for (int nt = 0; nt < 2; ++nt)
          acc[mt][nt] = __builtin_amdgcn_mfma_f32_16x16x32_bf16(af[mt], bx[nt], acc[mt][nt], 0, 0, 0);
    }
#pragma unroll
    for (int mt = 0; mt < 4; ++mt)
#pragma unroll
      for (int nt = 0; nt < 2; ++nt) {
        int tok = w * 32 + nt * 16 + l15, d0 = mt * 16 + quad * 4;
        char* a = RK + tok * 128 + (((d0 >> 3) ^ (tok & 7)) << 4) + (d0 & 7) * 2;
        *(unsigned int*)a = pkt(acc[mt][nt][0], acc[mt][nt][1]);
        *(unsigned int*)(a + 4) = pkt(acc[mt][nt][2], acc[mt][nt][3]);
      }
  }

  // ---- V projection: D[tok][d] (A = Xwin tokens, B = Wv) -> V^T in RVT
  {
    f4 acc[2][4];
#pragma unroll
    for (int a = 0; a < 2; ++a)
#pragma unroll
      for (int b2 = 0; b2 < 4; ++b2) acc[a][b2] = fz;
#pragma unroll
    for (int ks = 0; ks < 4; ++ks) {
      s8 ax[2], bw[4];
#pragma unroll
      for (int mt = 0; mt < 2; ++mt) {
        int rr = w * 32 + mt * 16 + l15;
        ax[mt] = *(const s8*)(RX + rr * 256 + (((ks * 4 + quad) ^ (rr & 15)) << 4));
      }
#pragma unroll
      for (int nt = 0; nt < 4; ++nt) {
        int rr = nt * 16 + l15;
        bw[nt] = *(const s8*)(RW + 32768 + rr * 256 + (((ks * 4 + quad) ^ (rr & 15)) << 4));
      }
#pragma unroll
      for (int mt = 0; mt < 2; ++mt)
#pragma unroll
        for (int nt = 0; nt < 4; ++nt)
          acc[mt][nt] = __builtin_amdgcn_mfma_f32_16x16x32_bf16(ax[mt], bw[nt], acc[mt][nt], 0, 0, 0);
    }
    __syncthreads();   // B: all RX reads + RK writes done
#pragma unroll
    for (int mt = 0; mt < 2; ++mt)
#pragma unroll
      for (int nt = 0; nt < 4; ++nt) {
        int d = nt * 16 + l15, t0 = w * 32 + mt * 16 + quad * 4;
        char* a = RVT + d * 512 + (((t0 >> 3) ^ (d & 31)) << 4) + (t0 & 7) * 2;
        *(unsigned int*)a = pkt(acc[mt][nt][0], acc[mt][nt][1]);
        *(unsigned int*)(a + 4) = pkt(acc[mt][nt][2], acc[mt][nt][3]);
      }
  }
  __syncthreads();   // C: RK + RVT ready -> flash

  // ---- flash (barrier-free): S^T = K.Q^T, P = exp2(S*c), O^T += V^T.P
  f4 o[4][2];
  float lsum[2] = {0.f, 0.f};
#pragma unroll
  for (int a = 0; a < 4; ++a) { o[a][0] = fz; o[a][1] = fz; }

  for (int jt = 0; jt < 4; ++jt) {
    f4 s[4][2];
#pragma unroll
    for (int a = 0; a < 4; ++a) { s[a][0] = fz; s[a][1] = fz; }
#pragma unroll
    for (int ks = 0; ks < 2; ++ks) {
      s8 af[4];
#pragma unroll
      for (int mt = 0; mt < 4; ++mt) {
        int rr = jt * 64 + mt * 16 + l15;
        af[mt] = *(const s8*)(RK + rr * 128 + (((ks * 4 + quad) ^ (rr & 7)) << 4));
      }
      __builtin_amdgcn_s_setprio(1);
#pragma unroll
      for (int mt = 0; mt < 4; ++mt)
#pragma unroll
        for (int nt = 0; nt < 2; ++nt)
          s[mt][nt] = __builtin_amdgcn_mfma_f32_16x16x32_bf16(af[mt], bq[nt][ks], s[mt][nt], 0, 0, 0);
      __builtin_amdgcn_s_setprio(0);
    }
    // P = exp2(s * scale*log2e); wave-private -> no barrier
#pragma unroll
    for (int mt = 0; mt < 4; ++mt)
#pragma unroll
      for (int nt = 0; nt < 2; ++nt) {
        float p0 = exp2f(s[mt][nt][0] * 0.18033688f);
        float p1 = exp2f(s[mt][nt][1] * 0.18033688f);
        float p2 = exp2f(s[mt][nt][2] * 0.18033688f);
        float p3 = exp2f(s[mt][nt][3] * 0.18033688f);
        lsum[nt] += p0 + p1 + p2 + p3;
        int iL = nt * 16 + l15, j0 = mt * 16 + quad * 4;
        char* a = Pw + iL * 128 + (((j0 >> 3) ^ (iL & 7)) << 4) + (j0 & 7) * 2;
        *(unsigned int*)a = pkt(p0, p1);
        *(unsigned int*)(a + 4) = pkt(p2, p3);
      }
#pragma unroll
    for (int ks = 0; ks < 2; ++ks) {
      s8 av[4], bp[2];
#pragma unroll
      for (int mt = 0; mt < 4; ++mt) {
        int d = mt * 16 + l15;
        av[mt] = *(const s8*)(RVT + d * 512 + (((jt * 8 + ks * 4 + quad) ^ (d & 31)) << 4));
      }
#pragma unroll
      for (int nt = 0; nt < 2; ++nt) {
        int iL = nt * 16 + l15;
        bp[nt] = *(const s8*)(Pw + iL * 128 + (((ks * 4 + quad) ^ (iL & 7)) << 4));
      }
      __builtin_amdgcn_s_setprio(1);
#pragma unroll
      for (int mt = 0; mt < 4; ++mt)
#pragma unroll
        for (int nt = 0; nt < 2; ++nt)
          o[mt][nt] = __builtin_amdgcn_mfma_f32_16x16x32_bf16(av[mt], bp[nt], o[mt][nt], 0, 0, 0);
      __builtin_amdgcn_s_setprio(0);
    }
  }

  // reduce l across quads (j-partials live in quads)
  float inv[2];
#pragma unroll
  for (int nt = 0; nt < 2; ++nt) {
    float v = lsum[nt];
    v += __shfl_xor(v, 16, 64);
    v += __shfl_xor(v, 32, 64);
    inv[nt] = 1.f / v;
  }
  // O -> RO (=RW region, dead since V proj; no barrier needed before write)
#pragma unroll
  for (int mt = 0; mt < 4; ++mt)
#pragma unroll
    for (int nt = 0; nt < 2; ++nt) {
      int i = w * 32 + nt * 16 + l15, d0 = mt * 16 + quad * 4;
      char* a = RO + i * 128 + (((d0 >> 3) ^ (i & 7)) << 4) + (d0 & 7) * 2;
      *(unsigned int*)a = pkt(o[mt][nt][0] * inv[nt], o[mt][nt][1] * inv[nt]);
      *(unsigned int*)(a + 4) = pkt(o[mt][nt][2] * inv[nt], o[mt][nt][3] * inv[nt]);
    }
  __syncthreads();   // D: O complete
  const int tok = tid >> 1, half = tid & 1;
  const int n = nbase + ((tok >> 4) << 8) + (tok & 15);
  ushort* dst = ao + (size_t)n * 512 + head * 64 + half * 32;
#pragma unroll
  for (int c = 0; c < 4; ++c) {
    u4v v = *(const u4v*)(RO + tok * 128 + (((half * 4 + c) ^ (tok & 7)) << 4));
    *(u4v*)(dst + c * 8) = v;
  }
}

// ---------------------------------------------------------------------------
extern "C" void kernel_launch(void* const* d_in, const int* in_sizes, int n_in,
                              void* d_out, int out_size, void* d_ws, size_t ws_size,
                              hipStream_t stream)
{
  const float* x_in    = (const float*)d_in[0];
  const float* ln1_g   = (const float*)d_in[1];
  const float* ln1_b   = (const float*)d_in[2];
  const float* wq      = (const float*)d_in[3];
  const float* wkv     = (const float*)d_in[4];
  const float* wo      = (const float*)d_in[5];
  const float* bo      = (const float*)d_in[6];
  const float* ln2_g   = (const float*)d_in[7];
  const float* ln2_b   = (const float*)d_in[8];
  const float* w_in    = (const float*)d_in[9];
  const float* b_in    = (const float*)d_in[10];
  const float* w_c3    = (const float*)d_in[11];
  const float* b_c3    = (const float*)d_in[12];
  const float* w_c1    = (const float*)d_in[13];
  const float* b_c1    = (const float*)d_in[14];
  const float* w_outer = (const float*)d_in[15];
  const float* b_outer = (const float*)d_in[16];

  char* wsb = (char*)d_ws;
  ushort* CW = (ushort*)wsb;                       // bf16 weights, 2.46 MB
  float*  TB = (float*)(wsb + 3145728);            // border-bias tables, 18 KB
  float*  XH = (float*)(wsb + 4194304);            // 32 MB residual x, NHWC f32
  ushort* XN = (ushort*)(wsb + 37748736);          // 16 MB LN out, NHWC bf16
  ushort* AO = (ushort*)(wsb + 54525952);          // 64 MB attn out [65536][512] bf16
  ushort* G  = (ushort*)(wsb + 138412032);         // 32 MB gelu out [65536][256] bf16
  ushort* XB = (ushort*)(wsb + 171966464);         // 16 MB bf16 copy of x

  const ushort* zp = CW + 1228800;
  dim3 b256(256);

  prep_w<<<dim3(4808), b256, 0, stream>>>(wq, wkv, wo, w_in, w_c3, w_c1, w_outer, CW);
  prep_fold<<<dim3(512), dim3(128), 0, stream>>>(w_c3, w_in, b_in, CW + 557056, TB);

  // ---- layer 0
  ln_nhwc<true><<<dim3(256), b256, 0, stream>>>(x_in, ln1_g, ln1_b, XN);
  attn_kernel<<<dim3(256, 8), dim3(512), 0, stream>>>(XN, CW, CW + 131072, AO);
  // wo-GEMM + residual(x NCHW) + fused ln2(l0) -> XH, XN
  gemm_nhwc<6><<<dim3(512, 1), b256, 0, stream>>>(CW + 393216, AO, bo, x_in, XH,
      nullptr, ln2_g, ln2_b, XN, 512, 128);
  conv3_kernel<<<dim3(512, 2), b256, 0, stream>>>(CW + 557056, XN, b_c3, G, zp, TB);
  // wc1-GEMM + residual + fused ln1(l1) -> XH, XN
  gemm_nhwc<5><<<dim3(512, 1), b256, 0, stream>>>(CW + 1146880, G, b_c1, XH, XH,
      nullptr, ln1_g + 128, ln1_b + 128, XN, 256, 128);

  // ---- layer 1
  attn_kernel<<<dim3(256, 8), dim3(512), 0, stream>>>(XN, CW + 65536, CW + 262144, AO);
  // wo-GEMM + residual + fused ln2(l1) -> XH, XN
  gemm_nhwc<5><<<dim3(512, 1), b256, 0, stream>>>(CW + 458752, AO, bo + 128, XH, XH,
      nullptr, ln2_g + 128, ln2_b + 128, XN, 512, 128);
  conv3_kernel<<<dim3(512, 2), b256, 0, stream>>>(CW + 851968, XN, b_c3 + 256, G, zp, TB + 2304);
  gemm_nhwc<3><<<dim3(512, 1), b256, 0, stream>>>(CW + 1179648, G, b_c1 + 128, XH, XH,
      XB, nullptr, nullptr, nullptr, 256, 128);

  gemm_nhwc<2><<<dim3(512, 1), b256, 0, stream>>>(CW + 1212416, XB, b_outer, XH, d_out,
      nullptr, nullptr, nullptr, nullptr, 128, 128);
}

// Round 9
// 574.409 us; speedup vs baseline: 1.0810x; 1.0810x over previous
//
#include <hip/hip_runtime.h>
#include <hip/hip_bf16.h>
#include <math.h>

typedef __hip_bfloat16 bf16;
typedef float f4 __attribute__((ext_vector_type(4)));
typedef short s8 __attribute__((ext_vector_type(8)));      // 8 bf16 fragment (4 VGPR)
typedef unsigned int u2 __attribute__((ext_vector_type(2)));
typedef unsigned int u4v __attribute__((ext_vector_type(4)));

// async global->LDS, 16B per lane; LDS dest = wave-uniform base + lane*16
__device__ __forceinline__ void gload16(const void* g, char* l) {
  __builtin_amdgcn_global_load_lds(
      (const __attribute__((address_space(1))) unsigned int*)g,
      (__attribute__((address_space(3))) unsigned int*)l, 16, 0, 0);
}
__device__ __forceinline__ unsigned short bfr(float f) {
  bf16 h = __float2bfloat16(f);
  return *(unsigned short*)&h;
}
__device__ __forceinline__ unsigned int pk2(float a, float b) {
  return (unsigned int)bfr(a) | ((unsigned int)bfr(b) << 16);
}
// truncating bf16x2 pack (lo=a, hi=b): 1 v_perm_b32
__device__ __forceinline__ unsigned int pkt(float a, float b) {
  return __builtin_amdgcn_perm(__float_as_uint(b), __float_as_uint(a), 0x07060302u);
}

// ---------------- weight prep: fp32 -> bf16 (+ zero page). w_in/w_c3 handled
// by prep_fold (w_in is folded into the 3x3 conv weights).
__global__ __launch_bounds__(256) void prep_w(
    const float* __restrict__ wq, const float* __restrict__ wkv,
    const float* __restrict__ wo, const float* __restrict__ win,
    const float* __restrict__ wc3, const float* __restrict__ wc1,
    const float* __restrict__ wout, ushort* __restrict__ cw)
{
  int i = blockIdx.x * 256 + threadIdx.x;
  float v;
  if (i < 131072) v = wq[i];
  else if (i < 393216) v = wkv[i - 131072];
  else if (i < 524288) v = wo[i - 393216];
  else if (i < 1146880) return;                  // w_in + w_c3 regions: prep_fold
  else if (i < 1212416) v = wc1[i - 1146880];
  else if (i < 1228800) v = wout[i - 1212416];
  else if (i < 1230848) { cw[i] = 0; return; }   // zero page
  else return;
  cw[i] = bfr(v);
}

// ---------------- fold w_in into w_c3:  wf[m][tap][i] = sum_c wc3[m][c][tap]*win[c][i]
// Also emits border-bias tables T[lyr][9][256] (see r7 notes).
__global__ __launch_bounds__(128) void prep_fold(
    const float* __restrict__ wc3, const float* __restrict__ win,
    const float* __restrict__ b_in, ushort* __restrict__ cw3out,
    float* __restrict__ T)
{
  __shared__ float col[128][9];
  __shared__ float sred[2][9];
  const int lyr = blockIdx.x >> 8, m = blockIdx.x & 255;
  const int tid = threadIdx.x;
  const float* src = wc3 + (((size_t)lyr * 256 + m) * 128 + tid) * 9;
#pragma unroll
  for (int t = 0; t < 9; ++t) col[tid][t] = src[t];
  float bi = b_in[lyr * 128 + tid];
  float sb[9];
#pragma unroll
  for (int t = 0; t < 9; ++t) {
    float v = col[tid][t] * bi;
    v += __shfl_xor(v, 1, 64);  v += __shfl_xor(v, 2, 64);
    v += __shfl_xor(v, 4, 64);  v += __shfl_xor(v, 8, 64);
    v += __shfl_xor(v, 16, 64); v += __shfl_xor(v, 32, 64);
    sb[t] = v;
  }
  if ((tid & 63) == 0) {
#pragma unroll
    for (int t = 0; t < 9; ++t) sred[tid >> 6][t] = sb[t];
  }
  __syncthreads();
  float acc[9] = {0.f,0.f,0.f,0.f,0.f,0.f,0.f,0.f,0.f};
  const float* wrow = win + (size_t)lyr * 16384 + tid;
  for (int c = 0; c < 128; ++c) {
    float wv = wrow[(size_t)c * 128];
#pragma unroll
    for (int t = 0; t < 9; ++t) acc[t] += col[c][t] * wv;
  }
  ushort* dst = cw3out + (size_t)lyr * 294912 + (size_t)m * 1152 + tid;
#pragma unroll
  for (int t = 0; t < 9; ++t) dst[t * 128] = bfr(acc[t]);
  if (tid == 0) {
    float s[9];
#pragma unroll
    for (int t = 0; t < 9; ++t) s[t] = sred[0][t] + sred[1][t];
    float* Tl = T + lyr * 2304;
    Tl[0 * 256 + m] = s[0]+s[1]+s[2]+s[3]+s[4]+s[5]+s[6]+s[7]+s[8];
    Tl[1 * 256 + m] = s[0] + s[1] + s[2];
    Tl[2 * 256 + m] = s[6] + s[7] + s[8];
    Tl[3 * 256 + m] = s[0] + s[3] + s[6];
    Tl[4 * 256 + m] = s[2] + s[5] + s[8];
    Tl[5 * 256 + m] = s[0];
    Tl[6 * 256 + m] = s[2];
    Tl[7 * 256 + m] = s[6];
    Tl[8 * 256 + m] = s[8];
  }
}

// ---------------- LayerNorm over channels -> NHWC bf16 (NCHW f32 input; only
// the first LN remains standalone — the rest are fused into GEMM epilogues)
template<bool NCHW>
__global__ __launch_bounds__(256) void ln_nhwc(
    const float* __restrict__ x, const float* __restrict__ g,
    const float* __restrict__ b, ushort* __restrict__ y)
{
  const int p = blockIdx.x * 256 + threadIdx.x;
  f4 v[32];
  float s = 0.f, s2 = 0.f;
  if constexpr (NCHW) {
#pragma unroll
    for (int i = 0; i < 32; ++i)
#pragma unroll
      for (int j = 0; j < 4; ++j) {
        float t = x[(size_t)(i * 4 + j) * 65536 + p];
        v[i][j] = t; s += t; s2 += t * t;
      }
  } else {
    const f4* base = (const f4*)(x + (size_t)p * 128);
#pragma unroll
    for (int i = 0; i < 32; ++i) {
      v[i] = base[i];
#pragma unroll
      for (int j = 0; j < 4; ++j) { s += v[i][j]; s2 += v[i][j] * v[i][j]; }
    }
  }
  float mean = s * (1.f / 128.f);
  float var = s2 * (1.f / 128.f) - mean * mean;
  var = var > 0.f ? var : 0.f;
  float inv = 1.f / (sqrtf(var) + 1e-5f);
  u2* dst = (u2*)(y + (size_t)p * 128);
#pragma unroll
  for (int i = 0; i < 32; ++i) {
    f4 gg = *(const f4*)(g + i * 4);
    f4 bb = *(const f4*)(b + i * 4);
    float f0 = (v[i][0] - mean) * inv * gg[0] + bb[0];
    float f1 = (v[i][1] - mean) * inv * gg[1] + bb[1];
    float f2 = (v[i][2] - mean) * inv * gg[2] + bb[2];
    float f3 = (v[i][3] - mean) * inv * gg[3] + bb[3];
    u2 st; st.x = pk2(f0, f1); st.y = pk2(f2, f3);
    dst[i] = st;
  }
}

// ---------------- MFMA GEMM: C_nhwc[n][m] = sum_k A[m][k] * X[n][k]
// MODE 0: bf16 out + bias
// MODE 1: f32 out + bias + res(NHWC f32)
// MODE 2: NCHW f32 out + bias + res(NHWC f32)
// MODE 3: MODE 1 + bf16 mirror to out2
// MODE 4: f32 out + bias + res(NCHW f32)
// MODE 5: MODE 1 + fused LayerNorm over the 128 out-channels -> xn (bf16 NHWC)
// MODE 6: MODE 4 + fused LayerNorm -> xn
// MODE 7: v = acc+bias+res(NHWC) kept in-register; then SECOND GEMM
//         out_nchw[m'][n] = sum_i A2[m'][i]*bf16(v)[i] + lng[m'] + v[m'] .
//         (fuses the w_outer GEMM into the l1 wc1 epilogue; needs M==128,
//          gridDim.y==1, 64KB LDS: W-tile @0 restaged, V-tile @32768.)
// LN/outer fusion requires M==128, gridDim.y==1 (block holds full channel vec).
template<int MODE>
__global__ __launch_bounds__(256) void gemm_nhwc(
    const ushort* __restrict__ A, const ushort* __restrict__ X,
    const float* __restrict__ bias, const float* __restrict__ res,
    void* __restrict__ out, ushort* __restrict__ out2,
    const ushort* __restrict__ A2,
    const float* __restrict__ lng, const float* __restrict__ lnb,
    ushort* __restrict__ xn, const int K, const int M)
{
  constexpr unsigned SMSZ = (MODE == 7) ? 65536u : 32768u;
  __shared__ __align__(16) char sm[SMSZ];   // A-tile [128][64] @0, X-tile @16384 (xor-swizzled)
  const int tid = threadIdx.x, w = tid >> 6, l = tid & 63;
  const int quad = l >> 4, l15 = l & 15;
  const int n0 = blockIdx.x * 128, m0 = blockIdx.y * 128;
  const int mh = (w & 1) * 64, nh = (w >> 1) * 64;
  const f4 fz = {0.f, 0.f, 0.f, 0.f};
  f4 acc[4][4];
#pragma unroll
  for (int a = 0; a < 4; ++a)
#pragma unroll
    for (int b2 = 0; b2 < 4; ++b2) acc[a][b2] = fz;

  const int KI = K >> 6;
  for (int kk = 0; kk < KI; ++kk) {
    if (kk) __syncthreads();
    const int k0 = kk << 6;
#pragma unroll
    for (int j = 0; j < 4; ++j) {
      int p = j * 256 + tid, r = p >> 3, c = (p & 7) ^ (r & 7);
      gload16(A + (size_t)(m0 + r) * K + k0 + c * 8, sm + (j * 256 + w * 64) * 16);
    }
#pragma unroll
    for (int j = 0; j < 4; ++j) {
      int p = j * 256 + tid, r = p >> 3, c = (p & 7) ^ (r & 7);
      gload16(X + (size_t)(n0 + r) * K + k0 + c * 8, sm + 16384 + (j * 256 + w * 64) * 16);
    }
    __syncthreads();
#pragma unroll
    for (int ks = 0; ks < 2; ++ks) {
      s8 af[4], bx[4];
#pragma unroll
      for (int mt = 0; mt < 4; ++mt) {
        int rr = mh + mt * 16 + l15;
        af[mt] = *(const s8*)(sm + rr * 128 + (((ks * 4 + quad) ^ (rr & 7)) << 4));
      }
#pragma unroll
      for (int nt = 0; nt < 4; ++nt) {
        int rr = nh + nt * 16 + l15;
        bx[nt] = *(const s8*)(sm + 16384 + rr * 128 + (((ks * 4 + quad) ^ (rr & 7)) << 4));
      }
#pragma unroll
      for (int mt = 0; mt < 4; ++mt)
#pragma unroll
        for (int nt = 0; nt < 4; ++nt)
          acc[mt][nt] = __builtin_amdgcn_mfma_f32_16x16x32_bf16(af[mt], bx[nt], acc[mt][nt], 0, 0, 0);
    }
  }

  if constexpr (MODE == 7) {
    // ---- phase 1: v = acc + bias + res(NHWC f32); pack bf16(v) -> V-tile LDS
    // V region @32768 untouched by K-loop -> no barrier needed before writes.
#pragma unroll
    for (int mt = 0; mt < 4; ++mt) {
      const int m = mh + mt * 16 + quad * 4;
      f4 bb = *(const f4*)(bias + m);
      const int seg = m >> 6, kl = m & 63;
#pragma unroll
      for (int nt = 0; nt < 4; ++nt) {
        const int r = nh + nt * 16 + l15;
        f4 v = acc[mt][nt] + bb + *(const f4*)(res + (size_t)(n0 + r) * 128 + m);
        acc[mt][nt] = v;
        u2 st; st.x = pk2(v[0], v[1]); st.y = pk2(v[2], v[3]);
        *(u2*)(sm + 32768 + seg * 16384 + r * 128 +
               (((kl >> 3) ^ (r & 7)) << 4) + (kl & 7) * 2) = st;
      }
    }
    __syncthreads();   // K-loop reads + V writes done -> restage W into @0
#pragma unroll
    for (int kk2 = 0; kk2 < 2; ++kk2)
#pragma unroll
      for (int j = 0; j < 4; ++j) {
        int p = j * 256 + tid, r = p >> 3, c = (p & 7) ^ (r & 7);
        gload16(A2 + (size_t)r * 128 + kk2 * 64 + c * 8,
                sm + kk2 * 16384 + (j * 256 + w * 64) * 16);
      }
    __syncthreads();
    f4 acc2[4][4];
#pragma unroll
    for (int a = 0; a < 4; ++a)
#pragma unroll
      for (int b2 = 0; b2 < 4; ++b2) acc2[a][b2] = fz;
#pragma unroll
    for (int kk2 = 0; kk2 < 2; ++kk2)
#pragma unroll
      for (int ks = 0; ks < 2; ++ks) {
        s8 af[4], bx[4];
#pragma unroll
        for (int mt = 0; mt < 4; ++mt) {
          int rr = mh + mt * 16 + l15;
          af[mt] = *(const s8*)(sm + kk2 * 16384 + rr * 128 + (((ks * 4 + quad) ^ (rr & 7)) << 4));
        }
#pragma unroll
        for (int nt = 0; nt < 4; ++nt) {
          int rr = nh + nt * 16 + l15;
          bx[nt] = *(const s8*)(sm + 32768 + kk2 * 16384 + rr * 128 + (((ks * 4 + quad) ^ (rr & 7)) << 4));
        }
#pragma unroll
        for (int mt = 0; mt < 4; ++mt)
#pragma unroll
          for (int nt = 0; nt < 4; ++nt)
            acc2[mt][nt] = __builtin_amdgcn_mfma_f32_16x16x32_bf16(af[mt], bx[nt], acc2[mt][nt], 0, 0, 0);
      }
    // ---- store: out NCHW = acc2 + b_outer(lng) + v (this thread's acc)
#pragma unroll
    for (int mt = 0; mt < 4; ++mt) {
      const int m = mh + mt * 16 + quad * 4;
      f4 bo2 = *(const f4*)(lng + m);
#pragma unroll
      for (int nt = 0; nt < 4; ++nt) {
        const int n = n0 + nh + nt * 16 + l15;
        f4 v2 = acc2[mt][nt] + bo2 + acc[mt][nt];
#pragma unroll
        for (int i = 0; i < 4; ++i)
          ((float*)out)[(size_t)(m + i) * 65536 + n] = v2[i];
      }
    }
    return;
  }

  if constexpr (MODE == 5 || MODE == 6) {
    // ---- fused bias + residual + write XH f32 + per-pixel LayerNorm -> xn
    float s1[4] = {0.f, 0.f, 0.f, 0.f}, s2[4] = {0.f, 0.f, 0.f, 0.f};
#pragma unroll
    for (int mt = 0; mt < 4; ++mt) {
      const int m = mh + mt * 16 + quad * 4;
      f4 bb = *(const f4*)(bias + m);
#pragma unroll
      for (int nt = 0; nt < 4; ++nt) {
        const int n = n0 + nh + nt * 16 + l15;
        f4 v = acc[mt][nt] + bb;
        if constexpr (MODE == 5) {
          f4 r = *(const f4*)(res + (size_t)n * 128 + m);
          v += r;
        } else {
          f4 r;
#pragma unroll
          for (int i = 0; i < 4; ++i) r[i] = res[(size_t)(m + i) * 65536 + n];
          v += r;
        }
        *(f4*)((float*)out + (size_t)n * 128 + m) = v;
        acc[mt][nt] = v;
        s1[nt] += v[0] + v[1] + v[2] + v[3];
        s2[nt] += v[0] * v[0] + v[1] * v[1] + v[2] * v[2] + v[3] * v[3];
      }
    }
    __syncthreads();               // all K-loop LDS reads done; reuse sm
    float* pb = (float*)sm;        // [2 halves][128 pixels][2] floats = 2KB
#pragma unroll
    for (int nt = 0; nt < 4; ++nt) {
      float a1 = s1[nt], a2 = s2[nt];
      a1 += __shfl_xor(a1, 16, 64); a1 += __shfl_xor(a1, 32, 64);
      a2 += __shfl_xor(a2, 16, 64); a2 += __shfl_xor(a2, 32, 64);
      s1[nt] = a1; s2[nt] = a2;
      if (quad == 0) {
        int pn = nh + nt * 16 + l15;
        pb[((w & 1) * 128 + pn) * 2]     = a1;
        pb[((w & 1) * 128 + pn) * 2 + 1] = a2;
      }
    }
    __syncthreads();
#pragma unroll
    for (int nt = 0; nt < 4; ++nt) {
      int pn = nh + nt * 16 + l15;
      float t1 = s1[nt] + pb[((1 - (w & 1)) * 128 + pn) * 2];
      float t2 = s2[nt] + pb[((1 - (w & 1)) * 128 + pn) * 2 + 1];
      float mean = t1 * (1.f / 128.f);
      float var = t2 * (1.f / 128.f) - mean * mean;
      var = var > 0.f ? var : 0.f;
      s1[nt] = mean;
      s2[nt] = 1.f / (sqrtf(var) + 1e-5f);
    }
#pragma unroll
    for (int mt = 0; mt < 4; ++mt) {
      const int m = mh + mt * 16 + quad * 4;
      f4 gg = *(const f4*)(lng + m);
      f4 b2 = *(const f4*)(lnb + m);
#pragma unroll
      for (int nt = 0; nt < 4; ++nt) {
        const int n = n0 + nh + nt * 16 + l15;
        f4 v = acc[mt][nt];
        float mean = s1[nt], inv = s2[nt];
        float f0 = (v[0] - mean) * inv * gg[0] + b2[0];
        float f1 = (v[1] - mean) * inv * gg[1] + b2[1];
        float f2 = (v[2] - mean) * inv * gg[2] + b2[2];
        float f3 = (v[3] - mean) * inv * gg[3] + b2[3];
        u2 st; st.x = pk2(f0, f1); st.y = pk2(f2, f3);
        *(u2*)(xn + (size_t)n * 128 + m) = st;
      }
    }
    return;
  }

#pragma unroll
  for (int mt = 0; mt < 4; ++mt) {
#pragma unroll
    for (int nt = 0; nt < 4; ++nt) {
      const int m = m0 + mh + mt * 16 + quad * 4;
      const int n = n0 + nh + nt * 16 + l15;
      f4 bb = *(const f4*)(bias + m);
      f4 v = acc[mt][nt] + bb;
      if constexpr (MODE == 0) {
        u2 st; st.x = pk2(v[0], v[1]); st.y = pk2(v[2], v[3]);
        *(u2*)((ushort*)out + (size_t)n * M + m) = st;
      } else if constexpr (MODE == 1 || MODE == 3) {
        f4 r = *(const f4*)(res + (size_t)n * M + m);
        v += r;
        *(f4*)((float*)out + (size_t)n * M + m) = v;
        if constexpr (MODE == 3) {
          u2 st; st.x = pk2(v[0], v[1]); st.y = pk2(v[2], v[3]);
          *(u2*)(out2 + (size_t)n * M + m) = st;
        }
      } else if constexpr (MODE == 4) {
        f4 r;
#pragma unroll
        for (int i = 0; i < 4; ++i) r[i] = res[(size_t)(m + i) * 65536 + n];
        v += r;
        *(f4*)((float*)out + (size_t)n * M + m) = v;
      } else {
        f4 r = *(const f4*)(res + (size_t)n * M + m);
#pragma unroll
        for (int i = 0; i < 4; ++i)
          ((float*)out)[(size_t)(m + i) * 65536 + n] = v[i] + r[i];
      }
    }
  }
}

// ---------------- 3x3 conv (w_in FOLDED IN) as implicit MFMA GEMM (K=9*128)
// + border-aware folded b_in + b_c3 + exact GELU -> bf16.
__global__ __launch_bounds__(256) void conv3_kernel(
    const ushort* __restrict__ A, const ushort* __restrict__ X,
    const float* __restrict__ bias, ushort* __restrict__ out,
    const ushort* __restrict__ zp, const float* __restrict__ T)
{
  __shared__ __align__(16) char sm[32768];
  const int tid = threadIdx.x, w = tid >> 6, l = tid & 63;
  const int quad = l >> 4, l15 = l & 15;
  const int n0 = blockIdx.x * 128, m0 = blockIdx.y * 128;
  const int mh = (w & 1) * 64, nh = (w >> 1) * 64;
  const f4 fz = {0.f, 0.f, 0.f, 0.f};
  f4 acc[4][4];
#pragma unroll
  for (int a = 0; a < 4; ++a)
#pragma unroll
    for (int b2 = 0; b2 < 4; ++b2) acc[a][b2] = fz;

  for (int kk = 0; kk < 18; ++kk) {
    if (kk) __syncthreads();
    const int tap = kk >> 1, ky = tap / 3, kx = tap - ky * 3;
    const int dn = (ky - 1) * 256 + (kx - 1);
    const int kseg = (kk & 1) << 6;
#pragma unroll
    for (int j = 0; j < 4; ++j) {
      int p = j * 256 + tid, r = p >> 3, c = (p & 7) ^ (r & 7);
      gload16(A + (size_t)(m0 + r) * 1152 + kk * 64 + c * 8, sm + (j * 256 + w * 64) * 16);
    }
#pragma unroll
    for (int j = 0; j < 4; ++j) {
      int p = j * 256 + tid, r = p >> 3, c = (p & 7) ^ (r & 7);
      int nl = n0 + r;
      int ys = (nl >> 8) + ky - 1, xs = (nl & 255) + kx - 1;
      const ushort* gp = ((unsigned)ys < 256u && (unsigned)xs < 256u)
                         ? X + (size_t)(nl + dn) * 128 + kseg + c * 8 : zp;
      gload16(gp, sm + 16384 + (j * 256 + w * 64) * 16);
    }
    __syncthreads();
#pragma unroll
    for (int ks = 0; ks < 2; ++ks) {
      s8 af[4], bx[4];
#pragma unroll
      for (int mt = 0; mt < 4; ++mt) {
        int rr = mh + mt * 16 + l15;
        af[mt] = *(const s8*)(sm + rr * 128 + (((ks * 4 + quad) ^ (rr & 7)) << 4));
      }
#pragma unroll
      for (int nt = 0; nt < 4; ++nt) {
        int rr = nh + nt * 16 + l15;
        bx[nt] = *(const s8*)(sm + 16384 + rr * 128 + (((ks * 4 + quad) ^ (rr & 7)) << 4));
      }
#pragma unroll
      for (int mt = 0; mt < 4; ++mt)
#pragma unroll
        for (int nt = 0; nt < 4; ++nt)
          acc[mt][nt] = __builtin_amdgcn_mfma_f32_16x16x32_bf16(af[mt], bx[nt], acc[mt][nt], 0, 0, 0);
    }
  }
  // epilogue: folded-bias with border correction, then GELU
  const int y = n0 >> 8;                 // block-uniform (block spans half a row)
  const bool y0 = (y == 0), y1 = (y == 255);
  const int xbase = (n0 & 255) + nh;
#pragma unroll
  for (int mt = 0; mt < 4; ++mt) {
    const int m = m0 + mh + mt * 16 + quad * 4;
    f4 base = *(const f4*)(bias + m) + *(const f4*)(T + m);
    f4 Lc = *(const f4*)(T + 3 * 256 + m);
    f4 Rc = *(const f4*)(T + 4 * 256 + m);
    if (y0) {
      base -= *(const f4*)(T + 1 * 256 + m);
      Lc -= *(const f4*)(T + 5 * 256 + m);
      Rc -= *(const f4*)(T + 6 * 256 + m);
    }
    if (y1) {
      base -= *(const f4*)(T + 2 * 256 + m);
      Lc -= *(const f4*)(T + 7 * 256 + m);
      Rc -= *(const f4*)(T + 8 * 256 + m);
    }
#pragma unroll
    for (int nt = 0; nt < 4; ++nt) {
      const int n = n0 + nh + nt * 16 + l15;
      const int x = xbase + nt * 16 + l15;
      float fx0 = (x == 0) ? 1.f : 0.f;
      float fx1 = (x == 255) ? 1.f : 0.f;
      f4 v = acc[mt][nt] + base - Lc * fx0 - Rc * fx1;
      float g0 = 0.5f * v[0] * (1.f + erff(v[0] * 0.70710678118f));
      float g1 = 0.5f * v[1] * (1.f + erff(v[1] * 0.70710678118f));
      float g2 = 0.5f * v[2] * (1.f + erff(v[2] * 0.70710678118f));
      float g3 = 0.5f * v[3] * (1.f + erff(v[3] * 0.70710678118f));
      u2 st; st.x = pk2(g0, g1); st.y = pk2(g2, g3);
      *(u2*)(out + (size_t)n * 256 + m) = st;
    }
  }
}

// ---------------- fully-fused window attention, 512 threads (8 waves) --------
// r5-proven kernel (118.5us): LDS 144KB, LDS-staged X/W, P in LDS, setprio on
// flash MFMA clusters. (in-register P via shuffle REGRESSED: ds_bpermute uses
// the LDS pipe, conflicts 4.98M->7.08M.)
__global__ __launch_bounds__(512) void attn_kernel(
    const ushort* __restrict__ xn, const ushort* __restrict__ wq,
    const ushort* __restrict__ wkv, ushort* __restrict__ ao)
{
  __shared__ __align__(16) char sm[147456];
  const int tid = threadIdx.x, w = tid >> 6, l = tid & 63;
  const int quad = l >> 4, l15 = l & 15;
  const int win = blockIdx.x, head = blockIdx.y;
  const int nbase = ((win >> 4) << 12) + ((win & 15) << 4);
  char* RX  = sm;                  // 65536
  char* RW  = sm + 65536;          // 49152: Wq@0, Wk@16384, Wv@32768; later O
  char* RK  = sm + 114688;         // 32768 [tok][64d]
  char* RVT = sm;                  // 32768 [64d][256tok]
  char* Pw  = sm + 32768 + w * 4096;  // wave-private P [32 i][64 j]
  char* RO  = RW;                  // O [256 tok][64 d]
  const f4 fz = {0.f, 0.f, 0.f, 0.f};

  // ---- stage Xwin [256 tok][128 ch] + Wq + Wk + Wv (single shot)
#pragma unroll
  for (int j = 0; j < 8; ++j) {
    int p = j * 512 + tid, r = p >> 4, c = (p & 15) ^ (r & 15);
    int n = nbase + ((r >> 4) << 8) + (r & 15);
    gload16(xn + (size_t)n * 128 + c * 8, RX + (j * 512 + w * 64) * 16);
  }
  {
    const ushort* wpq = wq + (size_t)head * 64 * 128;
    const ushort* wpk = wkv + (size_t)head * 64 * 128;
    const ushort* wpv = wkv + (size_t)(512 + head * 64) * 128;
#pragma unroll
    for (int j = 0; j < 2; ++j) {
      int p = j * 512 + tid, r = p >> 4, c = (p & 15) ^ (r & 15);
      gload16(wpq + (size_t)r * 128 + c * 8, RW + (j * 512 + w * 64) * 16);
    }
#pragma unroll
    for (int j = 0; j < 2; ++j) {
      int p = j * 512 + tid, r = p >> 4, c = (p & 15) ^ (r & 15);
      gload16(wpk + (size_t)r * 128 + c * 8, RW + 16384 + (j * 512 + w * 64) * 16);
    }
#pragma unroll
    for (int j = 0; j < 2; ++j) {
      int p = j * 512 + tid, r = p >> 4, c = (p & 15) ^ (r & 15);
      gload16(wpv + (size_t)r * 128 + c * 8, RW + 32768 + (j * 512 + w * 64) * 16);
    }
  }
  __syncthreads();   // A: Xwin + all W ready

  // ---- Q projection -> registers (B-fragment layout via shuffles)
  s8 bq[2][2];
  {
    f4 acc[4][2];
#pragma unroll
    for (int a = 0; a < 4; ++a) { acc[a][0] = fz; acc[a][1] = fz; }
#pragma unroll
    for (int ks = 0; ks < 4; ++ks) {
      s8 af[4], bx[2];
#pragma unroll
      for (int mt = 0; mt < 4; ++mt) {
        int rr = mt * 16 + l15;
        af[mt] = *(const s8*)(RW + rr * 256 + (((ks * 4 + quad) ^ (rr & 15)) << 4));
      }
#pragma unroll
      for (int nt = 0; nt < 2; ++nt) {
        int rr = w * 32 + nt * 16 + l15;
        bx[nt] = *(const s8*)(RX + rr * 256 + (((ks * 4 + quad) ^ (rr & 15)) << 4));
      }
#pragma unroll
      for (int mt = 0; mt < 4; ++mt)
#pragma unroll
        for (int nt = 0; nt < 2; ++nt)
          acc[mt][nt] = __builtin_amdgcn_mfma_f32_16x16x32_bf16(af[mt], bx[nt], acc[mt][nt], 0, 0, 0);
    }
    // C layout: lane(quad,l15) holds Q[d=mt*16+quad*4+reg][tok=w*32+nt*16+l15].
    // B-frag needs: lane(quad,l15) holds d=ks*32+quad*8+j at same tok.
#pragma unroll
    for (int nt = 0; nt < 2; ++nt) {
      unsigned pd[4][2];
#pragma unroll
      for (int mt = 0; mt < 4; ++mt) {
        pd[mt][0] = pkt(acc[mt][nt][0], acc[mt][nt][1]);
        pd[mt][1] = pkt(acc[mt][nt][2], acc[mt][nt][3]);
      }
#pragma unroll
      for (int ks = 0; ks < 2; ++ks) {
        u4v t;
#pragma unroll
        for (int dj = 0; dj < 4; ++dj) {
          int srcl = l15 + (((quad & 1) * 2 + (dj >> 1)) << 4);
          unsigned va = (unsigned)__shfl((int)pd[2 * ks][dj & 1], srcl, 64);
          unsigned vb = (unsigned)__shfl((int)pd[2 * ks + 1][dj & 1], srcl, 64);
          t[dj] = (quad < 2) ? va : vb;
        }
        bq[nt][ks] = __builtin_bit_cast(s8, t);
      }
    }
  }

  // ---- K projection -> RK [tok][64d] swizzled
  {
    f4 acc[4][2];
#pragma unroll
    for (int a = 0; a < 4; ++a) { acc[a][0] = fz; acc[a][1] = fz; }
#pragma unroll
    for (int ks = 0; ks < 4; ++ks) {
      s8 af[4], bx[2];
#pragma unroll
      for (int mt = 0; mt < 4; ++mt) {
        int rr = mt * 16 + l15;
        af[mt] = *(const s8*)(RW + 16384 + rr * 256 + (((ks * 4 + quad) ^ (rr & 15)) << 4));
      }
#pragma unroll
      for (int nt = 0; nt < 2; ++nt) {
        int rr = w * 32 + nt * 16 + l15;
        bx[nt] = *(const s8*)(RX + rr * 256 + (((ks * 4 + quad) ^ (rr & 15)) << 4));
      }
#pragma unroll
      for (int mt = 0; mt < 4; ++mt)
#pragma unroll
        for (int nt = 0; nt < 2; ++nt)
          acc[mt][nt] = __builtin_amdgcn_mfma_f32_16x16x32_bf16(af[mt], bx[nt], acc[mt][nt], 0, 0, 0);
    }
#pragma unroll
    for (int mt = 0; mt < 4; ++mt)
#pragma unroll
      for (int nt = 0; nt < 2; ++nt) {
        int tok = w * 32 + nt * 16 + l15, d0 = mt * 16 + quad * 4;
        char* a = RK + tok * 128 + (((d0 >> 3) ^ (tok & 7)) << 4) + (d0 & 7) * 2;
        *(unsigned int*)a = pkt(acc[mt][nt][0], acc[mt][nt][1]);
        *(unsigned int*)(a + 4) = pkt(acc[mt][nt][2], acc[mt][nt][3]);
      }
  }

  // ---- V projection: D[tok][d] (A = Xwin tokens, B = Wv) -> V^T in RVT
  {
    f4 acc[2][4];
#pragma unroll
    for (int a = 0; a < 2; ++a)
#pragma unroll
      for (int b2 = 0; b2 < 4; ++b2) acc[a][b2] = fz;
#pragma unroll
    for (int ks = 0; ks < 4; ++ks) {
      s8 ax[2], bw[4];
#pragma unroll
      for (int mt = 0; mt < 2; ++mt) {
        int rr = w * 32 + mt * 16 + l15;
        ax[mt] = *(const s8*)(RX + rr * 256 + (((ks * 4 + quad) ^ (rr & 15)) << 4));
      }
#pragma unroll
      for (int nt = 0; nt < 4; ++nt) {
        int rr = nt * 16 + l15;
        bw[nt] = *(const s8*)(RW + 32768 + rr * 256 + (((ks * 4 + quad) ^ (rr & 15)) << 4));
      }
#pragma unroll
      for (int mt = 0; mt < 2; ++mt)
#pragma unroll
        for (int nt = 0; nt < 4; ++nt)
          acc[mt][nt] = __builtin_amdgcn_mfma_f32_16x16x32_bf16(ax[mt], bw[nt], acc[mt][nt], 0, 0, 0);
    }
    __syncthreads();   // B: all RX reads + RK writes done
#pragma unroll
    for (int mt = 0; mt < 2; ++mt)
#pragma unroll
      for (int nt = 0; nt < 4; ++nt) {
        int d = nt * 16 + l15, t0 = w * 32 + mt * 16 + quad * 4;
        char* a = RVT + d * 512 + (((t0 >> 3) ^ (d & 31)) << 4) + (t0 & 7) * 2;
        *(unsigned int*)a = pkt(acc[mt][nt][0], acc[mt][nt][1]);
        *(unsigned int*)(a + 4) = pkt(acc[mt][nt][2], acc[mt][nt][3]);
      }
  }
  __syncthreads();   // C: RK + RVT ready -> flash

  // ---- flash (barrier-free): S^T = K.Q^T, P = exp2(S*c), O^T += V^T.P
  f4 o[4][2];
  float lsum[2] = {0.f, 0.f};
#pragma unroll
  for (int a = 0; a < 4; ++a) { o[a][0] = fz; o[a][1] = fz; }

  for (int jt = 0; jt < 4; ++jt) {
    f4 s[4][2];
#pragma unroll
    for (int a = 0; a < 4; ++a) { s[a][0] = fz; s[a][1] = fz; }
#pragma unroll
    for (int ks = 0; ks < 2; ++ks) {
      s8 af[4];
#pragma unroll
      for (int mt = 0; mt < 4; ++mt) {
        int rr = jt * 64 + mt * 16 + l15;
        af[mt] = *(const s8*)(RK + rr * 128 + (((ks * 4 + quad) ^ (rr & 7)) << 4));
      }
      __builtin_amdgcn_s_setprio(1);
#pragma unroll
      for (int mt = 0; mt < 4; ++mt)
#pragma unroll
        for (int nt = 0; nt < 2; ++nt)
          s[mt][nt] = __builtin_amdgcn_mfma_f32_16x16x32_bf16(af[mt], bq[nt][ks], s[mt][nt], 0, 0, 0);
      __builtin_amdgcn_s_setprio(0);
    }
    // P = exp2(s * scale*log2e); wave-private -> no barrier
#pragma unroll
    for (int mt = 0; mt < 4; ++mt)
#pragma unroll
      for (int nt = 0; nt < 2; ++nt) {
        float p0 = exp2f(s[mt][nt][0] * 0.18033688f);
        float p1 = exp2f(s[mt][nt][1] * 0.18033688f);
        float p2 = exp2f(s[mt][nt][2] * 0.18033688f);
        float p3 = exp2f(s[mt][nt][3] * 0.18033688f);
        lsum[nt] += p0 + p1 + p2 + p3;
        int iL = nt * 16 + l15, j0 = mt * 16 + quad * 4;
        char* a = Pw + iL * 128 + (((j0 >> 3) ^ (iL & 7)) << 4) + (j0 & 7) * 2;
        *(unsigned int*)a = pkt(p0, p1);
        *(unsigned int*)(a + 4) = pkt(p2, p3);
      }
#pragma unroll
    for (int ks = 0; ks < 2; ++ks) {
      s8 av[4], bp[2];
#pragma unroll
      for (int mt = 0; mt < 4; ++mt) {
        int d = mt * 16 + l15;
        av[mt] = *(const s8*)(RVT + d * 512 + (((jt * 8 + ks * 4 + quad) ^ (d & 31)) << 4));
      }
#pragma unroll
      for (int nt = 0; nt < 2; ++nt) {
        int iL = nt * 16 + l15;
        bp[nt] = *(const s8*)(Pw + iL * 128 + (((ks * 4 + quad) ^ (iL & 7)) << 4));
      }
      __builtin_amdgcn_s_setprio(1);
#pragma unroll
      for (int mt = 0; mt < 4; ++mt)
#pragma unroll
        for (int nt = 0; nt < 2; ++nt)
          o[mt][nt] = __builtin_amdgcn_mfma_f32_16x16x32_bf16(av[mt], bp[nt], o[mt][nt], 0, 0, 0);
      __builtin_amdgcn_s_setprio(0);
    }
  }

  // reduce l across quads (j-partials live in quads)
  float inv[2];
#pragma unroll
  for (int nt = 0; nt < 2; ++nt) {
    float v = lsum[nt];
    v += __shfl_xor(v, 16, 64);
    v += __shfl_xor(v, 32, 64);
    inv[nt] = 1.f / v;
  }
  // O -> RO (=RW region, dead since V proj; no barrier needed before write)
#pragma unroll
  for (int mt = 0; mt < 4; ++mt)
#pragma unroll
    for (int nt = 0; nt < 2; ++nt) {
      int i = w * 32 + nt * 16 + l15, d0 = mt * 16 + quad * 4;
      char* a = RO + i * 128 + (((d0 >> 3) ^ (i & 7)) << 4) + (d0 & 7) * 2;
      *(unsigned int*)a = pkt(o[mt][nt][0] * inv[nt], o[mt][nt][1] * inv[nt]);
      *(unsigned int*)(a + 4) = pkt(o[mt][nt][2] * inv[nt], o[mt][nt][3] * inv[nt]);
    }
  __syncthreads();   // D: O complete
  const int tok = tid >> 1, half = tid & 1;
  const int n = nbase + ((tok >> 4) << 8) + (tok & 15);
  ushort* dst = ao + (size_t)n * 512 + head * 64 + half * 32;
#pragma unroll
  for (int c = 0; c < 4; ++c) {
    u4v v = *(const u4v*)(RO + tok * 128 + (((half * 4 + c) ^ (tok & 7)) << 4));
    *(u4v*)(dst + c * 8) = v;
  }
}

// ---------------------------------------------------------------------------
extern "C" void kernel_launch(void* const* d_in, const int* in_sizes, int n_in,
                              void* d_out, int out_size, void* d_ws, size_t ws_size,
                              hipStream_t stream)
{
  const float* x_in    = (const float*)d_in[0];
  const float* ln1_g   = (const float*)d_in[1];
  const float* ln1_b   = (const float*)d_in[2];
  const float* wq      = (const float*)d_in[3];
  const float* wkv     = (const float*)d_in[4];
  const float* wo      = (const float*)d_in[5];
  const float* bo      = (const float*)d_in[6];
  const float* ln2_g   = (const float*)d_in[7];
  const float* ln2_b   = (const float*)d_in[8];
  const float* w_in    = (const float*)d_in[9];
  const float* b_in    = (const float*)d_in[10];
  const float* w_c3    = (const float*)d_in[11];
  const float* b_c3    = (const float*)d_in[12];
  const float* w_c1    = (const float*)d_in[13];
  const float* b_c1    = (const float*)d_in[14];
  const float* w_outer = (const float*)d_in[15];
  const float* b_outer = (const float*)d_in[16];

  char* wsb = (char*)d_ws;
  ushort* CW = (ushort*)wsb;                       // bf16 weights, 2.46 MB
  float*  TB = (float*)(wsb + 3145728);            // border-bias tables, 18 KB
  float*  XH = (float*)(wsb + 4194304);            // 32 MB residual x, NHWC f32
  ushort* XN = (ushort*)(wsb + 37748736);          // 16 MB LN out, NHWC bf16
  ushort* AO = (ushort*)(wsb + 54525952);          // 64 MB attn out [65536][512] bf16
  ushort* G  = (ushort*)(wsb + 138412032);         // 32 MB gelu out [65536][256] bf16

  const ushort* zp = CW + 1228800;
  dim3 b256(256);

  prep_w<<<dim3(4808), b256, 0, stream>>>(wq, wkv, wo, w_in, w_c3, w_c1, w_outer, CW);
  prep_fold<<<dim3(512), dim3(128), 0, stream>>>(w_c3, w_in, b_in, CW + 557056, TB);

  // ---- layer 0
  ln_nhwc<true><<<dim3(256), b256, 0, stream>>>(x_in, ln1_g, ln1_b, XN);
  attn_kernel<<<dim3(256, 8), dim3(512), 0, stream>>>(XN, CW, CW + 131072, AO);
  // wo-GEMM + residual(x NCHW) + fused ln2(l0) -> XH, XN
  gemm_nhwc<6><<<dim3(512, 1), b256, 0, stream>>>(CW + 393216, AO, bo, x_in, XH,
      nullptr, nullptr, ln2_g, ln2_b, XN, 512, 128);
  conv3_kernel<<<dim3(512, 2), b256, 0, stream>>>(CW + 557056, XN, b_c3, G, zp, TB);
  // wc1-GEMM + residual + fused ln1(l1) -> XH, XN
  gemm_nhwc<5><<<dim3(512, 1), b256, 0, stream>>>(CW + 1146880, G, b_c1, XH, XH,
      nullptr, nullptr, ln1_g + 128, ln1_b + 128, XN, 256, 128);

  // ---- layer 1
  attn_kernel<<<dim3(256, 8), dim3(512), 0, stream>>>(XN, CW + 65536, CW + 262144, AO);
  // wo-GEMM + residual + fused ln2(l1) -> XH, XN
  gemm_nhwc<5><<<dim3(512, 1), b256, 0, stream>>>(CW + 458752, AO, bo + 128, XH, XH,
      nullptr, nullptr, ln2_g + 128, ln2_b + 128, XN, 512, 128);
  conv3_kernel<<<dim3(512, 2), b256, 0, stream>>>(CW + 851968, XN, b_c3 + 256, G, zp, TB + 2304);
  // wc1-GEMM (l1) + residual + FUSED w_outer GEMM + b_outer + final residual
  //   -> d_out (NCHW f32).  Eliminates XH/XB round-trip + gemm<2> launch.
  gemm_nhwc<7><<<dim3(512, 1), b256, 0, stream>>>(CW + 1179648, G, b_c1 + 128, XH, d_out,
      nullptr, CW + 1212416, b_outer, nullptr, nullptr, 256, 128);
}